// Round 4
// baseline (236.238 us; speedup 1.0000x reference)
//
#include <hip/hip_runtime.h>
#include <math.h>

#define D 256
#define M 8
#define P 4
#define FL 4
#define L 300
#define N 8
#define S 13294
#define NM 64
#define CH 32   // D / M
#define R_Q (L * N)   // 2400 query rows
#define BN_P 384      // loc(256) + wgt(128) outputs

typedef __attribute__((ext_vector_type(8))) short short8v;
typedef __attribute__((ext_vector_type(4))) float f32x4;
typedef __attribute__((ext_vector_type(4))) unsigned short ushort4v;

__device__ __forceinline__ unsigned short f2bf(float f) {
  unsigned u = __builtin_bit_cast(unsigned, f);
  u += 0x7FFFu + ((u >> 16) & 1u);   // round-to-nearest-even
  return (unsigned short)(u >> 16);
}

// ---------------------------------------------------------------------------
// Kernel W: convert W1 (f32 [d][c]) -> bf16 [d][c] once.
// ---------------------------------------------------------------------------
__global__ __launch_bounds__(256) void convert_w1(
    const float* __restrict__ W1, unsigned short* __restrict__ W1b) {
  int i = (blockIdx.x * 256 + threadIdx.x) * 4;
  float4 v = *(const float4*)(W1 + i);
  ushort4v r;
  r.x = f2bf(v.x); r.y = f2bf(v.y); r.z = f2bf(v.z); r.w = f2bf(v.w);
  *(ushort4v*)(W1b + i) = r;
}

// ---------------------------------------------------------------------------
// Kernel A v2: value_t[n, s, d] = b1[d] + sum_c W1[d,c] * k[n,c,s] (bf16 MFMA)
// - B (W1b) fragments read DIRECTLY from global (L2-resident, no LDS tile)
// - A (k) staged via 2-buffer LDS pipeline, ONE barrier per K-step:
//   loads for step i+1 issued before frag-read+MFMA of step i, written after.
// LDS = 2 x 9.2 KB -> occupancy is VGPR-bound (launch_bounds 3 waves/EU).
// ---------------------------------------------------------------------------
#define APITCH 72

__global__ __launch_bounds__(256, 3) void value_gemm_mfma(
    const float* __restrict__ kin, const unsigned short* __restrict__ W1b,
    const float* __restrict__ b1, float* __restrict__ value_t) {
  const int s_base = blockIdx.x * 64;
  const int nb = blockIdx.y;
  const int t = threadIdx.x;
  const int lane = t & 63;
  const int wave = t >> 6;
  const int wsr = wave & 1;   // s-half (32 rows)
  const int wdc = wave >> 1;  // d-half (128 cols)
  __shared__ unsigned short As[2][64 * APITCH];  // [s][c] per buffer
  f32x4 acc[2][8];
#pragma unroll
  for (int m = 0; m < 2; ++m)
#pragma unroll
    for (int n = 0; n < 8; ++n) acc[m][n] = (f32x4)0.f;
  const float* kn = kin + (size_t)nb * ((size_t)D * S);
  const bool full = (s_base + 64 <= S);
  const int c_my = t >> 4;         // 0..15 base c within 16-group
  const int s4 = (t & 15) * 4;     // 4 s-values per thread

  float av[4][4];                   // staged k values: [ci][s-sub]
  // ---- load step 0 ----
#pragma unroll
  for (int ci = 0; ci < 4; ++ci) {
    int c = ci * 16 + c_my;
    const float* src = kn + (size_t)c * S + s_base + s4;
    if (full) {
      float2 p0 = *(const float2*)src;
      float2 p1 = *(const float2*)(src + 2);
      av[ci][0] = p0.x; av[ci][1] = p0.y; av[ci][2] = p1.x; av[ci][3] = p1.y;
    } else {
      int gs = s_base + s4;
      av[ci][0] = (gs < S) ? src[0] : 0.f;
      av[ci][1] = (gs + 1 < S) ? src[1] : 0.f;
      av[ci][2] = (gs + 2 < S) ? src[2] : 0.f;
      av[ci][3] = (gs + 3 < S) ? src[3] : 0.f;
    }
  }
#pragma unroll
  for (int ci = 0; ci < 4; ++ci) {
    unsigned short* dst = As[0] + s4 * APITCH + ci * 16 + c_my;
    dst[0] = f2bf(av[ci][0]);
    dst[APITCH] = f2bf(av[ci][1]);
    dst[2 * APITCH] = f2bf(av[ci][2]);
    dst[3 * APITCH] = f2bf(av[ci][3]);
  }
  __syncthreads();

  const unsigned short* wbase = W1b + (size_t)(wdc * 128 + (lane & 15)) * D + (lane >> 4) * 8;

  for (int step = 0; step < 4; ++step) {
    const int buf = step & 1;
    // ---- issue global loads for step+1 (overlap with MFMA below) ----
    if (step < 3) {
      int k0n = (step + 1) * 64;
#pragma unroll
      for (int ci = 0; ci < 4; ++ci) {
        int c = k0n + ci * 16 + c_my;
        const float* src = kn + (size_t)c * S + s_base + s4;
        if (full) {
          float2 p0 = *(const float2*)src;
          float2 p1 = *(const float2*)(src + 2);
          av[ci][0] = p0.x; av[ci][1] = p0.y; av[ci][2] = p1.x; av[ci][3] = p1.y;
        } else {
          int gs = s_base + s4;
          av[ci][0] = (gs < S) ? src[0] : 0.f;
          av[ci][1] = (gs + 1 < S) ? src[1] : 0.f;
          av[ci][2] = (gs + 2 < S) ? src[2] : 0.f;
          av[ci][3] = (gs + 3 < S) ? src[3] : 0.f;
        }
      }
    }
    // ---- A fragments from LDS ----
    short8v af[2][2];
#pragma unroll
    for (int m = 0; m < 2; ++m)
#pragma unroll
      for (int kk = 0; kk < 2; ++kk)
        af[m][kk] = *(const short8v*)(As[buf] + (wsr * 32 + m * 16 + (lane & 15)) * APITCH
                                      + kk * 32 + (lane >> 4) * 8);
    // ---- MFMA, B-fragments straight from global (L2) ----
#pragma unroll
    for (int n = 0; n < 8; ++n) {
      const unsigned short* brow = wbase + (size_t)(n * 16) * D + step * 64;
      short8v b0 = *(const short8v*)(brow);
      short8v b1v = *(const short8v*)(brow + 32);
#pragma unroll
      for (int m = 0; m < 2; ++m) {
        acc[m][n] = __builtin_amdgcn_mfma_f32_16x16x32_bf16(af[m][0], b0, acc[m][n], 0, 0, 0);
        acc[m][n] = __builtin_amdgcn_mfma_f32_16x16x32_bf16(af[m][1], b1v, acc[m][n], 0, 0, 0);
      }
    }
    // ---- write next tile into the other buffer ----
    if (step < 3) {
#pragma unroll
      for (int ci = 0; ci < 4; ++ci) {
        unsigned short* dst = As[buf ^ 1] + s4 * APITCH + ci * 16 + c_my;
        dst[0] = f2bf(av[ci][0]);
        dst[APITCH] = f2bf(av[ci][1]);
        dst[2 * APITCH] = f2bf(av[ci][2]);
        dst[3 * APITCH] = f2bf(av[ci][3]);
      }
    }
    __syncthreads();
  }
  // ---- epilogue: C/D layout col=lane&15 (d), row=(lane>>4)*4+reg (s) ----
#pragma unroll
  for (int n = 0; n < 8; ++n) {
    int dloc = wdc * 128 + n * 16 + (lane & 15);
    float bias = b1[dloc];
#pragma unroll
    for (int m = 0; m < 2; ++m) {
      int sloc = wsr * 32 + m * 16 + (lane >> 4) * 4;
      int gs = s_base + sloc;
#pragma unroll
      for (int r = 0; r < 4; ++r) {
        if (gs + r < S)
          value_t[((size_t)nb * S + gs + r) * D + dloc] = acc[m][n][r] + bias;
      }
    }
  }
}

// ---------------------------------------------------------------------------
// Kernel P1: proj[r, o] = q[r,:] . W[o,:]  for W = [LW; GW] (384 outputs).
// ---------------------------------------------------------------------------
#define VG_PITCH 72
__global__ __launch_bounds__(256) void proj_gemm_mfma(
    const float* __restrict__ q, const float* __restrict__ LW,
    const float* __restrict__ LB, const float* __restrict__ GW,
    const float* __restrict__ GB, float* __restrict__ proj) {
  const int r_base = blockIdx.x * 64;
  const int t = threadIdx.x;
  const int lane = t & 63;
  const int wave = t >> 6;
  const int wsr = wave & 1;
  const int wdc = wave >> 1;
  __shared__ unsigned short As[64 * VG_PITCH];
  __shared__ unsigned short Bs[BN_P * VG_PITCH];
  f32x4 acc[2][12];
#pragma unroll
  for (int m = 0; m < 2; ++m)
#pragma unroll
    for (int n = 0; n < 12; ++n) acc[m][n] = (f32x4)0.f;
  for (int k0 = 0; k0 < D; k0 += 64) {
#pragma unroll
    for (int it = 0; it < 4; ++it) {
      int e = it * 256 + t;
      int row = e >> 4;
      int c4 = (e & 15) * 4;
      int gr = r_base + row;
      float4 v = (gr < R_Q) ? *(const float4*)(q + (size_t)gr * D + k0 + c4)
                            : make_float4(0.f, 0.f, 0.f, 0.f);
      ushort4v o;
      o.x = f2bf(v.x); o.y = f2bf(v.y); o.z = f2bf(v.z); o.w = f2bf(v.w);
      *(ushort4v*)(As + row * VG_PITCH + c4) = o;
    }
#pragma unroll
    for (int it = 0; it < 24; ++it) {
      int e = it * 256 + t;
      int col = e >> 4;
      int c4 = (e & 15) * 4;
      const float* src = (col < 256) ? (LW + (size_t)col * D + k0 + c4)
                                     : (GW + (size_t)(col - 256) * D + k0 + c4);
      float4 v = *(const float4*)src;
      ushort4v o;
      o.x = f2bf(v.x); o.y = f2bf(v.y); o.z = f2bf(v.z); o.w = f2bf(v.w);
      *(ushort4v*)(Bs + col * VG_PITCH + c4) = o;
    }
    __syncthreads();
    short8v af[2][2];
#pragma unroll
    for (int m = 0; m < 2; ++m)
#pragma unroll
      for (int kk = 0; kk < 2; ++kk)
        af[m][kk] = *(const short8v*)(As + (wsr * 32 + m * 16 + (lane & 15)) * VG_PITCH
                                      + kk * 32 + (lane >> 4) * 8);
#pragma unroll
    for (int n = 0; n < 12; ++n) {
      const unsigned short* brow = Bs + (wdc * 192 + n * 16 + (lane & 15)) * VG_PITCH
                                   + (lane >> 4) * 8;
      short8v b0 = *(const short8v*)(brow);
      short8v b1v = *(const short8v*)(brow + 32);
#pragma unroll
      for (int m = 0; m < 2; ++m) {
        acc[m][n] = __builtin_amdgcn_mfma_f32_16x16x32_bf16(af[m][0], b0, acc[m][n], 0, 0, 0);
        acc[m][n] = __builtin_amdgcn_mfma_f32_16x16x32_bf16(af[m][1], b1v, acc[m][n], 0, 0, 0);
      }
    }
    __syncthreads();
  }
#pragma unroll
  for (int n = 0; n < 12; ++n) {
    int col = wdc * 192 + n * 16 + (lane & 15);
    float bias = (col < 256) ? LB[col] : GB[col - 256];
#pragma unroll
    for (int m = 0; m < 2; ++m) {
      int row0 = r_base + wsr * 32 + m * 16 + (lane >> 4) * 4;
#pragma unroll
      for (int r = 0; r < 4; ++r) {
        if (row0 + r < R_Q)
          proj[(size_t)(row0 + r) * BN_P + col] = acc[m][n][r] + bias;
      }
    }
  }
}

// ---------------------------------------------------------------------------
// Kernel P2: per (l, n): softmax + grid computation from proj.
// ---------------------------------------------------------------------------
__global__ __launch_bounds__(256) void proj_post(
    const float* __restrict__ proj, const float* __restrict__ pc,
    const float* __restrict__ vsc, float* __restrict__ Gws,
    float* __restrict__ WTws, float* __restrict__ attn_out) {
  const int blk = blockIdx.x;  // l*N + n
  const int l = blk / N, n = blk % N;
  const int t = threadIdx.x;
  __shared__ float locs[256];
  __shared__ float wgts[128];
  locs[t] = proj[(size_t)blk * BN_P + t];
  if (t < 128) wgts[t] = proj[(size_t)blk * BN_P + 256 + t];
  __syncthreads();
  if (t < 8) {
    float mx = -1e30f;
    for (int j = 0; j < 16; ++j) mx = fmaxf(mx, wgts[t * 16 + j]);
    float e[16], sum = 0.f;
    for (int j = 0; j < 16; ++j) { e[j] = expf(wgts[t * 16 + j] - mx); sum += e[j]; }
    float inv = 1.f / sum;
    for (int j = 0; j < 16; ++j) wgts[t * 16 + j] = e[j] * inv;
  }
  __syncthreads();
  {
    int m = t >> 5, p = (t >> 3) & 3, f = (t >> 1) & 3, xy = t & 1;
    float cs  = 1.f / (1.f + expf(-pc[blk * 4 + xy]));
    float whs = 1.f / (1.f + expf(-pc[blk * 4 + 2 + xy]));
    float gpv = (xy == 0) ? ((p + 0.5f) * (1.f / P)) : ((m + 0.5f) * (1.f / M));
    float vsv = vsc[(n * FL + f) * 2 + xy];
    float g = (locs[t] * whs * (1.f / P) + (cs - 0.5f * whs) + gpv * whs) * (2.f * vsv) - 1.f;
    int nm = n * M + m;
    Gws[((size_t)(l * NM + nm) * 16 + f * P + p) * 2 + xy] = g;
    attn_out[((((size_t)n * L + l) * FL + f) * M + m) * (P * 3) + p * 3 + xy] = (g + 1.f) * 0.5f;
  }
  if (t < 128) {
    int m = t >> 4, jj = t & 15, f = jj >> 2, p = jj & 3;
    int nm = n * M + m;
    WTws[(size_t)(l * NM + nm) * 16 + jj] = wgts[t];
    attn_out[((((size_t)n * L + l) * FL + f) * M + m) * (P * 3) + p * 3 + 2] = wgts[t];
  }
}

// ---------------------------------------------------------------------------
// Kernel C: bilinear sampling + weighted sum over the 16 (f,p) points.
// ---------------------------------------------------------------------------
__global__ __launch_bounds__(512) void sample_kernel(
    const float* __restrict__ value_t, const float* __restrict__ Gws,
    const float* __restrict__ WTws, float* __restrict__ out_pre) {
  const int blk = blockIdx.x;  // l*NM + nm
  const int l = blk >> 6;
  const int nm = blk & 63;
  const int n = nm >> 3, m = nm & 7;
  const int t = threadIdx.x;
  const int j = t >> 5, ch = t & 31;
  __shared__ float Gs[32];
  __shared__ float Ws[16];
  __shared__ float red[16][33];
  if (t < 32) Gs[t] = Gws[(size_t)blk * 32 + t];
  else if (t < 48) Ws[t - 32] = WTws[(size_t)blk * 16 + (t - 32)];
  __syncthreads();
  const int f = j >> 2;
  const int Wl[4] = {100, 50, 25, 13};
  const int OFF[4] = {0, 10000, 12500, 13125};
  const int Wf = Wl[f], Hf = Wl[f], off = OFF[f];
  float gx = Gs[j * 2], gy = Gs[j * 2 + 1];
  float x = (gx + 1.f) * (Wf * 0.5f) - 0.5f;
  float y = (gy + 1.f) * (Hf * 0.5f) - 0.5f;
  float x0f = floorf(x), y0f = floorf(y);
  int x0 = (int)x0f, y0 = (int)y0f;
  float wx1 = x - x0f, wy1 = y - y0f;
  float wx0 = 1.f - wx1, wy0 = 1.f - wy1;
  const float* base = value_t + ((size_t)n * S + off) * D + m * CH + ch;
  float v00 = 0.f, v01 = 0.f, v10 = 0.f, v11 = 0.f;
  bool xv0 = (x0 >= 0) && (x0 < Wf), xv1 = (x0 + 1 >= 0) && (x0 + 1 < Wf);
  bool yv0 = (y0 >= 0) && (y0 < Hf), yv1 = (y0 + 1 >= 0) && (y0 + 1 < Hf);
  if (yv0) {
    if (xv0) v00 = base[(size_t)(y0 * Wf + x0) * D];
    if (xv1) v01 = base[(size_t)(y0 * Wf + x0 + 1) * D];
  }
  if (yv1) {
    if (xv0) v10 = base[(size_t)((y0 + 1) * Wf + x0) * D];
    if (xv1) v11 = base[(size_t)((y0 + 1) * Wf + x0 + 1) * D];
  }
  float val = wx0 * wy0 * v00 + wx1 * wy0 * v01 + wx0 * wy1 * v10 + wx1 * wy1 * v11;
  red[j][ch] = Ws[j] * val;
  __syncthreads();
  if (t < 32) {
    float s = 0.f;
#pragma unroll
    for (int jj = 0; jj < 16; ++jj) s += red[jj][t];
    out_pre[(size_t)(l * N + n) * D + m * CH + t] = s;
  }
}

// ---------------------------------------------------------------------------
// Kernel D: out[r, o] = b2[o] + sum_c out_pre[r, c] * W2[o, c]
// ---------------------------------------------------------------------------
__global__ __launch_bounds__(256) void out_gemm(
    const float* __restrict__ A, const float* __restrict__ W2,
    const float* __restrict__ b2, float* __restrict__ out) {
  const int r0 = blockIdx.x * 64;
  const int o0 = blockIdx.y * 64;
  __shared__ float As[32][65];
  __shared__ float Bs[32][65];
  const int t = threadIdx.x;
  const int tn = t & 15, tm = t >> 4;
  float acc[4][4] = {};
  const int R = L * N;
  for (int k0 = 0; k0 < D; k0 += 32) {
#pragma unroll
    for (int i = 0; i < 8; ++i) {
      int e = i * 256 + t;
      int c = e & 31, r = e >> 5;
      int gr = r0 + r;
      As[c][r] = (gr < R) ? A[(size_t)gr * D + k0 + c] : 0.f;
    }
#pragma unroll
    for (int i = 0; i < 8; ++i) {
      int e = i * 256 + t;
      int c = e & 31, o = e >> 5;
      Bs[c][o] = W2[(size_t)(o0 + o) * D + k0 + c];
    }
    __syncthreads();
#pragma unroll
    for (int kk = 0; kk < 32; ++kk) {
      float a[4], b[4];
#pragma unroll
      for (int i = 0; i < 4; ++i) a[i] = As[kk][tm * 4 + i];
#pragma unroll
      for (int j = 0; j < 4; ++j) b[j] = Bs[kk][tn * 4 + j];
#pragma unroll
      for (int i = 0; i < 4; ++i)
#pragma unroll
        for (int j = 0; j < 4; ++j) acc[i][j] = fmaf(a[i], b[j], acc[i][j]);
    }
    __syncthreads();
  }
#pragma unroll
  for (int i = 0; i < 4; ++i) {
    int gr = r0 + tm * 4 + i;
    if (gr >= R) continue;
#pragma unroll
    for (int j = 0; j < 4; ++j) {
      int go = o0 + tn * 4 + j;
      out[(size_t)gr * D + go] = acc[i][j] + b2[go];
    }
  }
}

extern "C" void kernel_launch(void* const* d_in, const int* in_sizes, int n_in,
                              void* d_out, int out_size, void* d_ws, size_t ws_size,
                              hipStream_t stream) {
  const float* q  = (const float*)d_in[0];
  const float* k  = (const float*)d_in[2];
  const float* pc = (const float*)d_in[5];
  const float* vs = (const float*)d_in[6];
  const float* W1 = (const float*)d_in[7];
  const float* b1 = (const float*)d_in[8];
  const float* W2 = (const float*)d_in[9];
  const float* b2 = (const float*)d_in[10];
  const float* LW = (const float*)d_in[11];
  const float* LB = (const float*)d_in[12];
  const float* GW = (const float*)d_in[13];
  const float* GB = (const float*)d_in[14];

  char* ws = (char*)d_ws;
  float* value_t = (float*)ws;                                   // [N,S,D]
  size_t off = (size_t)N * S * D * sizeof(float);
  float* Gws = (float*)(ws + off); off += (size_t)L * NM * 16 * 2 * sizeof(float);
  float* WT  = (float*)(ws + off); off += (size_t)L * NM * 16 * sizeof(float);
  float* out_pre = (float*)(ws + off); off += (size_t)L * N * D * sizeof(float);
  unsigned short* W1b = (unsigned short*)(ws + off); off += (size_t)D * D * sizeof(unsigned short);
  float* proj = (float*)(ws + off); off += (size_t)R_Q * BN_P * sizeof(float);

  float* out  = (float*)d_out;
  float* attn = out + (size_t)L * N * D;

  convert_w1<<<dim3(D * D / (256 * 4)), 256, 0, stream>>>(W1, W1b);
  value_gemm_mfma<<<dim3((S + 63) / 64, N), 256, 0, stream>>>(k, W1b, b1, value_t);
  proj_gemm_mfma<<<dim3((R_Q + 63) / 64), 256, 0, stream>>>(q, LW, LB, GW, GB, proj);
  proj_post<<<dim3(L * N), 256, 0, stream>>>(proj, pc, vs, Gws, WT, attn);
  sample_kernel<<<dim3(L * NM), 512, 0, stream>>>(value_t, Gws, WT, out_pre);
  out_gemm<<<dim3((L * N + 63) / 64, D / 64), 256, 0, stream>>>(out_pre, W2, b2, out);
}

// Round 5
// 212.177 us; speedup vs baseline: 1.1134x; 1.1134x over previous
//
#include <hip/hip_runtime.h>
#include <math.h>

#define D 256
#define M 8
#define P 4
#define FL 4
#define L 300
#define N 8
#define S 13294
#define NM 64
#define CH 32   // D / M
#define R_Q (L * N)   // 2400 query rows
#define BN_P 384      // loc(256) + wgt(128) outputs

typedef __attribute__((ext_vector_type(8))) short short8v;
typedef __attribute__((ext_vector_type(4))) float f32x4;
typedef __attribute__((ext_vector_type(4))) unsigned short ushort4v;

__device__ __forceinline__ unsigned short f2bf(float f) {
  unsigned u = __builtin_bit_cast(unsigned, f);
  u += 0x7FFFu + ((u >> 16) & 1u);   // round-to-nearest-even
  return (unsigned short)(u >> 16);
}

// ---------------------------------------------------------------------------
// Kernel W: convert W1 (f32 [d][c]) -> bf16 [d][c] once.
// ---------------------------------------------------------------------------
__global__ __launch_bounds__(256) void convert_w1(
    const float* __restrict__ W1, unsigned short* __restrict__ W1b) {
  int i = (blockIdx.x * 256 + threadIdx.x) * 4;
  float4 v = *(const float4*)(W1 + i);
  ushort4v r;
  r.x = f2bf(v.x); r.y = f2bf(v.y); r.z = f2bf(v.z); r.w = f2bf(v.w);
  *(ushort4v*)(W1b + i) = r;
}

// ---------------------------------------------------------------------------
// Kernel A v3: value_t[n, s, d] = b1[d] + sum_c W1[d,c] * k[n,c,s] (bf16 MFMA)
// R2 structure (both operands LDS-staged, 2-barrier lockstep) with:
//  - BN=128 per block (blockIdx.x = d-half) -> LDS 27.6 KB -> ~5 blocks/CU
//  - A staged as thread=s-row, 16 coalesced f32 loads, 4 packed ds_write_b64
//    (pitch 144 B: phase-level 2-way = free; kills R2's 8-way b16 scatter)
//  - fragment reads unchanged: b128 @ pitch 72 shorts (2-way free, 16B-aligned)
// ---------------------------------------------------------------------------
#define APITCH 72
#define BPITCH 72

__global__ __launch_bounds__(256) void value_gemm_mfma(
    const float* __restrict__ kin, const unsigned short* __restrict__ W1b,
    const float* __restrict__ b1, float* __restrict__ value_t) {
  const int d0 = blockIdx.x * 128;      // d-half; x fastest so pair shares A-tile
  const int s_base = blockIdx.y * 64;
  const int nb = blockIdx.z;
  const int t = threadIdx.x;
  const int lane = t & 63;
  const int wave = t >> 6;
  const int wsr = wave & 1;   // s-half (32 rows)
  const int wdc = wave >> 1;  // d-quarter within block (64 cols)
  __shared__ unsigned short As[64 * APITCH];   // [s][c]
  __shared__ unsigned short Bs[128 * BPITCH];  // [d][c]
  f32x4 acc[2][4];
#pragma unroll
  for (int m = 0; m < 2; ++m)
#pragma unroll
    for (int n = 0; n < 4; ++n) acc[m][n] = (f32x4)0.f;
  const float* kn = kin + (size_t)nb * ((size_t)D * S);
  const int gsA = s_base + lane;        // this thread's s-row
  const bool sok = gsA < S;
  const float* ksrc = kn + gsA;

  for (int step = 0; step < 4; ++step) {
    const int k0 = step * 64;
    // ---- stage A: wave covers c in [wave*16, wave*16+16); lane = s-row ----
    float va[16];
#pragma unroll
    for (int j = 0; j < 16; ++j) {
      int c = k0 + wave * 16 + j;
      va[j] = sok ? ksrc[(size_t)c * S] : 0.f;
    }
#pragma unroll
    for (int jq = 0; jq < 4; ++jq) {
      ushort4v w;
      w.x = f2bf(va[jq * 4 + 0]);
      w.y = f2bf(va[jq * 4 + 1]);
      w.z = f2bf(va[jq * 4 + 2]);
      w.w = f2bf(va[jq * 4 + 3]);
      *(ushort4v*)(As + lane * APITCH + wave * 16 + jq * 4) = w;
    }
    // ---- stage B: 128 d-rows x 64 c, b128 copies from W1b ----
#pragma unroll
    for (int it = 0; it < 4; ++it) {
      int e = it * 256 + t;
      int row = e >> 3;           // 0..127
      int cc = (e & 7) * 8;
      short8v v = *(const short8v*)(W1b + (size_t)(d0 + row) * D + k0 + cc);
      *(short8v*)(Bs + row * BPITCH + cc) = v;
    }
    __syncthreads();
    // ---- fragments + MFMA: per wave 2m x 4n x 2kk = 16 MFMA ----
    short8v af[2][2];
#pragma unroll
    for (int m = 0; m < 2; ++m)
#pragma unroll
      for (int kk = 0; kk < 2; ++kk)
        af[m][kk] = *(const short8v*)(As + (wsr * 32 + m * 16 + (lane & 15)) * APITCH
                                      + kk * 32 + (lane >> 4) * 8);
#pragma unroll
    for (int n = 0; n < 4; ++n) {
      const unsigned short* brow = Bs + (wdc * 64 + n * 16 + (lane & 15)) * BPITCH
                                   + (lane >> 4) * 8;
      short8v b0 = *(const short8v*)(brow);
      short8v b1v = *(const short8v*)(brow + 32);
#pragma unroll
      for (int m = 0; m < 2; ++m) {
        acc[m][n] = __builtin_amdgcn_mfma_f32_16x16x32_bf16(af[m][0], b0, acc[m][n], 0, 0, 0);
        acc[m][n] = __builtin_amdgcn_mfma_f32_16x16x32_bf16(af[m][1], b1v, acc[m][n], 0, 0, 0);
      }
    }
    __syncthreads();
  }
  // ---- epilogue: C/D layout col=lane&15 (d), row=(lane>>4)*4+reg (s) ----
#pragma unroll
  for (int n = 0; n < 4; ++n) {
    int dloc = d0 + wdc * 64 + n * 16 + (lane & 15);
    float bias = b1[dloc];
#pragma unroll
    for (int m = 0; m < 2; ++m) {
      int sloc = wsr * 32 + m * 16 + (lane >> 4) * 4;
      int gs = s_base + sloc;
#pragma unroll
      for (int r = 0; r < 4; ++r) {
        if (gs + r < S)
          value_t[((size_t)nb * S + gs + r) * D + dloc] = acc[m][n][r] + bias;
      }
    }
  }
}

// ---------------------------------------------------------------------------
// Kernel P1: proj[r, o] = q[r,:] . W[o,:]  for W = [LW; GW] (384 outputs).
// ---------------------------------------------------------------------------
#define VG_PITCH 72
__global__ __launch_bounds__(256) void proj_gemm_mfma(
    const float* __restrict__ q, const float* __restrict__ LW,
    const float* __restrict__ LB, const float* __restrict__ GW,
    const float* __restrict__ GB, float* __restrict__ proj) {
  const int r_base = blockIdx.x * 64;
  const int t = threadIdx.x;
  const int lane = t & 63;
  const int wave = t >> 6;
  const int wsr = wave & 1;
  const int wdc = wave >> 1;
  __shared__ unsigned short As[64 * VG_PITCH];
  __shared__ unsigned short Bs[BN_P * VG_PITCH];
  f32x4 acc[2][12];
#pragma unroll
  for (int m = 0; m < 2; ++m)
#pragma unroll
    for (int n = 0; n < 12; ++n) acc[m][n] = (f32x4)0.f;
  for (int k0 = 0; k0 < D; k0 += 64) {
#pragma unroll
    for (int it = 0; it < 4; ++it) {
      int e = it * 256 + t;
      int row = e >> 4;
      int c4 = (e & 15) * 4;
      int gr = r_base + row;
      float4 v = (gr < R_Q) ? *(const float4*)(q + (size_t)gr * D + k0 + c4)
                            : make_float4(0.f, 0.f, 0.f, 0.f);
      ushort4v o;
      o.x = f2bf(v.x); o.y = f2bf(v.y); o.z = f2bf(v.z); o.w = f2bf(v.w);
      *(ushort4v*)(As + row * VG_PITCH + c4) = o;
    }
#pragma unroll
    for (int it = 0; it < 24; ++it) {
      int e = it * 256 + t;
      int col = e >> 4;
      int c4 = (e & 15) * 4;
      const float* src = (col < 256) ? (LW + (size_t)col * D + k0 + c4)
                                     : (GW + (size_t)(col - 256) * D + k0 + c4);
      float4 v = *(const float4*)src;
      ushort4v o;
      o.x = f2bf(v.x); o.y = f2bf(v.y); o.z = f2bf(v.z); o.w = f2bf(v.w);
      *(ushort4v*)(Bs + col * VG_PITCH + c4) = o;
    }
    __syncthreads();
    short8v af[2][2];
#pragma unroll
    for (int m = 0; m < 2; ++m)
#pragma unroll
      for (int kk = 0; kk < 2; ++kk)
        af[m][kk] = *(const short8v*)(As + (wsr * 32 + m * 16 + (lane & 15)) * VG_PITCH
                                      + kk * 32 + (lane >> 4) * 8);
#pragma unroll
    for (int n = 0; n < 12; ++n) {
      const unsigned short* brow = Bs + (wdc * 192 + n * 16 + (lane & 15)) * VG_PITCH
                                   + (lane >> 4) * 8;
      short8v b0 = *(const short8v*)(brow);
      short8v b1v = *(const short8v*)(brow + 32);
#pragma unroll
      for (int m = 0; m < 2; ++m) {
        acc[m][n] = __builtin_amdgcn_mfma_f32_16x16x32_bf16(af[m][0], b0, acc[m][n], 0, 0, 0);
        acc[m][n] = __builtin_amdgcn_mfma_f32_16x16x32_bf16(af[m][1], b1v, acc[m][n], 0, 0, 0);
      }
    }
    __syncthreads();
  }
#pragma unroll
  for (int n = 0; n < 12; ++n) {
    int col = wdc * 192 + n * 16 + (lane & 15);
    float bias = (col < 256) ? LB[col] : GB[col - 256];
#pragma unroll
    for (int m = 0; m < 2; ++m) {
      int row0 = r_base + wsr * 32 + m * 16 + (lane >> 4) * 4;
#pragma unroll
      for (int r = 0; r < 4; ++r) {
        if (row0 + r < R_Q)
          proj[(size_t)(row0 + r) * BN_P + col] = acc[m][n][r] + bias;
      }
    }
  }
}

// ---------------------------------------------------------------------------
// Kernel P2: per (l, n): softmax + grid computation from proj.
// ---------------------------------------------------------------------------
__global__ __launch_bounds__(256) void proj_post(
    const float* __restrict__ proj, const float* __restrict__ pc,
    const float* __restrict__ vsc, float* __restrict__ Gws,
    float* __restrict__ WTws, float* __restrict__ attn_out) {
  const int blk = blockIdx.x;  // l*N + n
  const int l = blk / N, n = blk % N;
  const int t = threadIdx.x;
  __shared__ float locs[256];
  __shared__ float wgts[128];
  locs[t] = proj[(size_t)blk * BN_P + t];
  if (t < 128) wgts[t] = proj[(size_t)blk * BN_P + 256 + t];
  __syncthreads();
  if (t < 8) {
    float mx = -1e30f;
    for (int j = 0; j < 16; ++j) mx = fmaxf(mx, wgts[t * 16 + j]);
    float e[16], sum = 0.f;
    for (int j = 0; j < 16; ++j) { e[j] = expf(wgts[t * 16 + j] - mx); sum += e[j]; }
    float inv = 1.f / sum;
    for (int j = 0; j < 16; ++j) wgts[t * 16 + j] = e[j] * inv;
  }
  __syncthreads();
  {
    int m = t >> 5, p = (t >> 3) & 3, f = (t >> 1) & 3, xy = t & 1;
    float cs  = 1.f / (1.f + expf(-pc[blk * 4 + xy]));
    float whs = 1.f / (1.f + expf(-pc[blk * 4 + 2 + xy]));
    float gpv = (xy == 0) ? ((p + 0.5f) * (1.f / P)) : ((m + 0.5f) * (1.f / M));
    float vsv = vsc[(n * FL + f) * 2 + xy];
    float g = (locs[t] * whs * (1.f / P) + (cs - 0.5f * whs) + gpv * whs) * (2.f * vsv) - 1.f;
    int nm = n * M + m;
    Gws[((size_t)(l * NM + nm) * 16 + f * P + p) * 2 + xy] = g;
    attn_out[((((size_t)n * L + l) * FL + f) * M + m) * (P * 3) + p * 3 + xy] = (g + 1.f) * 0.5f;
  }
  if (t < 128) {
    int m = t >> 4, jj = t & 15, f = jj >> 2, p = jj & 3;
    int nm = n * M + m;
    WTws[(size_t)(l * NM + nm) * 16 + jj] = wgts[t];
    attn_out[((((size_t)n * L + l) * FL + f) * M + m) * (P * 3) + p * 3 + 2] = wgts[t];
  }
}

// ---------------------------------------------------------------------------
// Kernel C: bilinear sampling + weighted sum over the 16 (f,p) points.
// ---------------------------------------------------------------------------
__global__ __launch_bounds__(512) void sample_kernel(
    const float* __restrict__ value_t, const float* __restrict__ Gws,
    const float* __restrict__ WTws, float* __restrict__ out_pre) {
  const int blk = blockIdx.x;  // l*NM + nm
  const int l = blk >> 6;
  const int nm = blk & 63;
  const int n = nm >> 3, m = nm & 7;
  const int t = threadIdx.x;
  const int j = t >> 5, ch = t & 31;
  __shared__ float Gs[32];
  __shared__ float Ws[16];
  __shared__ float red[16][33];
  if (t < 32) Gs[t] = Gws[(size_t)blk * 32 + t];
  else if (t < 48) Ws[t - 32] = WTws[(size_t)blk * 16 + (t - 32)];
  __syncthreads();
  const int f = j >> 2;
  const int Wl[4] = {100, 50, 25, 13};
  const int OFF[4] = {0, 10000, 12500, 13125};
  const int Wf = Wl[f], Hf = Wl[f], off = OFF[f];
  float gx = Gs[j * 2], gy = Gs[j * 2 + 1];
  float x = (gx + 1.f) * (Wf * 0.5f) - 0.5f;
  float y = (gy + 1.f) * (Hf * 0.5f) - 0.5f;
  float x0f = floorf(x), y0f = floorf(y);
  int x0 = (int)x0f, y0 = (int)y0f;
  float wx1 = x - x0f, wy1 = y - y0f;
  float wx0 = 1.f - wx1, wy0 = 1.f - wy1;
  const float* base = value_t + ((size_t)n * S + off) * D + m * CH + ch;
  float v00 = 0.f, v01 = 0.f, v10 = 0.f, v11 = 0.f;
  bool xv0 = (x0 >= 0) && (x0 < Wf), xv1 = (x0 + 1 >= 0) && (x0 + 1 < Wf);
  bool yv0 = (y0 >= 0) && (y0 < Hf), yv1 = (y0 + 1 >= 0) && (y0 + 1 < Hf);
  if (yv0) {
    if (xv0) v00 = base[(size_t)(y0 * Wf + x0) * D];
    if (xv1) v01 = base[(size_t)(y0 * Wf + x0 + 1) * D];
  }
  if (yv1) {
    if (xv0) v10 = base[(size_t)((y0 + 1) * Wf + x0) * D];
    if (xv1) v11 = base[(size_t)((y0 + 1) * Wf + x0 + 1) * D];
  }
  float val = wx0 * wy0 * v00 + wx1 * wy0 * v01 + wx0 * wy1 * v10 + wx1 * wy1 * v11;
  red[j][ch] = Ws[j] * val;
  __syncthreads();
  if (t < 32) {
    float s = 0.f;
#pragma unroll
    for (int jj = 0; jj < 16; ++jj) s += red[jj][t];
    out_pre[(size_t)(l * N + n) * D + m * CH + t] = s;
  }
}

// ---------------------------------------------------------------------------
// Kernel D: out[r, o] = b2[o] + sum_c out_pre[r, c] * W2[o, c]
// ---------------------------------------------------------------------------
__global__ __launch_bounds__(256) void out_gemm(
    const float* __restrict__ A, const float* __restrict__ W2,
    const float* __restrict__ b2, float* __restrict__ out) {
  const int r0 = blockIdx.x * 64;
  const int o0 = blockIdx.y * 64;
  __shared__ float As[32][65];
  __shared__ float Bs[32][65];
  const int t = threadIdx.x;
  const int tn = t & 15, tm = t >> 4;
  float acc[4][4] = {};
  const int R = L * N;
  for (int k0 = 0; k0 < D; k0 += 32) {
#pragma unroll
    for (int i = 0; i < 8; ++i) {
      int e = i * 256 + t;
      int c = e & 31, r = e >> 5;
      int gr = r0 + r;
      As[c][r] = (gr < R) ? A[(size_t)gr * D + k0 + c] : 0.f;
    }
#pragma unroll
    for (int i = 0; i < 8; ++i) {
      int e = i * 256 + t;
      int c = e & 31, o = e >> 5;
      Bs[c][o] = W2[(size_t)(o0 + o) * D + k0 + c];
    }
    __syncthreads();
#pragma unroll
    for (int kk = 0; kk < 32; ++kk) {
      float a[4], b[4];
#pragma unroll
      for (int i = 0; i < 4; ++i) a[i] = As[kk][tm * 4 + i];
#pragma unroll
      for (int j = 0; j < 4; ++j) b[j] = Bs[kk][tn * 4 + j];
#pragma unroll
      for (int i = 0; i < 4; ++i)
#pragma unroll
        for (int j = 0; j < 4; ++j) acc[i][j] = fmaf(a[i], b[j], acc[i][j]);
    }
    __syncthreads();
  }
#pragma unroll
  for (int i = 0; i < 4; ++i) {
    int gr = r0 + tm * 4 + i;
    if (gr >= R) continue;
#pragma unroll
    for (int j = 0; j < 4; ++j) {
      int go = o0 + tn * 4 + j;
      out[(size_t)gr * D + go] = acc[i][j] + b2[go];
    }
  }
}

extern "C" void kernel_launch(void* const* d_in, const int* in_sizes, int n_in,
                              void* d_out, int out_size, void* d_ws, size_t ws_size,
                              hipStream_t stream) {
  const float* q  = (const float*)d_in[0];
  const float* k  = (const float*)d_in[2];
  const float* pc = (const float*)d_in[5];
  const float* vs = (const float*)d_in[6];
  const float* W1 = (const float*)d_in[7];
  const float* b1 = (const float*)d_in[8];
  const float* W2 = (const float*)d_in[9];
  const float* b2 = (const float*)d_in[10];
  const float* LW = (const float*)d_in[11];
  const float* LB = (const float*)d_in[12];
  const float* GW = (const float*)d_in[13];
  const float* GB = (const float*)d_in[14];

  char* ws = (char*)d_ws;
  float* value_t = (float*)ws;                                   // [N,S,D]
  size_t off = (size_t)N * S * D * sizeof(float);
  float* Gws = (float*)(ws + off); off += (size_t)L * NM * 16 * 2 * sizeof(float);
  float* WT  = (float*)(ws + off); off += (size_t)L * NM * 16 * sizeof(float);
  float* out_pre = (float*)(ws + off); off += (size_t)L * N * D * sizeof(float);
  unsigned short* W1b = (unsigned short*)(ws + off); off += (size_t)D * D * sizeof(unsigned short);
  float* proj = (float*)(ws + off); off += (size_t)R_Q * BN_P * sizeof(float);

  float* out  = (float*)d_out;
  float* attn = out + (size_t)L * N * D;

  convert_w1<<<dim3(D * D / (256 * 4)), 256, 0, stream>>>(W1, W1b);
  value_gemm_mfma<<<dim3(2, (S + 63) / 64, N), 256, 0, stream>>>(k, W1b, b1, value_t);
  proj_gemm_mfma<<<dim3((R_Q + 63) / 64), 256, 0, stream>>>(q, LW, LB, GW, GB, proj);
  proj_post<<<dim3(L * N), 256, 0, stream>>>(proj, pc, vs, Gws, WT, attn);
  sample_kernel<<<dim3(L * NM), 512, 0, stream>>>(value_t, Gws, WT, out_pre);
  out_gemm<<<dim3((L * N + 63) / 64, D / 64), 256, 0, stream>>>(out_pre, W2, b2, out);
}